// Round 6
// baseline (130.339 us; speedup 1.0000x reference)
//
#include <hip/hip_runtime.h>
#include <hip/hip_bf16.h>

#define BB 2
#define CC 64
#define HH 64
#define TT 512
#define FF 64
#define DD 32

typedef short short8 __attribute__((ext_vector_type(8)));
typedef float f32x4  __attribute__((ext_vector_type(4)));

__device__ __forceinline__ unsigned short f2bf(float x) {
    union { float f; unsigned u; } v; v.f = x;
    unsigned r = v.u + 0x7FFFu + ((v.u >> 16) & 1u);   // RNE
    return (unsigned short)(r >> 16);
}
__device__ __forceinline__ float bf2f(unsigned short h) {
    union { unsigned u; float f; } v; v.u = ((unsigned)h) << 16;
    return v.f;
}

// ---------------------------------------------------------------------------
// K1 (MFMA): Qb = bf16(w_mic @ x_mic + b_mic); Kb likewise.
// A = xT (m=f), B = W (n=h); 4 t per block (W staged once per 4 t).
// ---------------------------------------------------------------------------
__global__ __launch_bounds__(256) void k_qk(
    const float* __restrict__ x_mic, const float* __restrict__ x_ref,
    const float* __restrict__ w_mic, const float* __restrict__ b_mic,
    const float* __restrict__ w_ref, const float* __restrict__ b_ref,
    unsigned short* __restrict__ Qb, unsigned short* __restrict__ Kb)
{
    __shared__ unsigned short Wl[64 * 72];       // [h][c] pitch 72
    __shared__ unsigned short Xt[4][64 * 72];    // [t][f][c] pitch 72
    __shared__ float Bs[64];

    const int tid = threadIdx.x;
    const int b   = blockIdx.x >> 7;
    const int t0  = (blockIdx.x & 127) * 4;
    const int which = blockIdx.y;

    const float* xsrc = which ? x_ref : x_mic;
    const float* wsrc = which ? w_ref : w_mic;
    const float* bsrc = which ? b_ref : b_mic;
    unsigned short* outb = which ? Kb : Qb;

    const int l  = tid & 63;
    const int w  = tid >> 6;
    const int q  = l >> 4;
    const int nl = l & 15;

    // ---- stage W as bf16 [h][c] pitch 72 ----
    {
        const float4* wg = reinterpret_cast<const float4*>(wsrc);
        const int h  = tid >> 2;
        #pragma unroll
        for (int p = 0; p < 4; ++p) {
            const int c0 = (tid & 3) * 4 + p * 16;
            float4 wv = wg[h * 16 + (c0 >> 2)];
            unsigned w0 = (unsigned)f2bf(wv.x) | ((unsigned)f2bf(wv.y) << 16);
            unsigned w1 = (unsigned)f2bf(wv.z) | ((unsigned)f2bf(wv.w) << 16);
            uint2* dst = reinterpret_cast<uint2*>(&Wl[h * 72 + c0]);
            *dst = make_uint2(w0, w1);
        }
    }
    if (tid < 64) Bs[tid] = bsrc[tid];

    // ---- stage x transposed: xT[f][c] bf16, quad-shuffle 4x4 transpose ----
    {
        const float4* xg = reinterpret_cast<const float4*>(
            xsrc + (size_t)b * CC * TT * FF);
        #pragma unroll
        for (int t = 0; t < 4; ++t) {
            #pragma unroll
            for (int p = 0; p < 4; ++p) {
                const int cbase = p * 16 + 4 * w;
                const int c     = cbase + q;
                float4 xv = xg[((size_t)c * TT + (t0 + t)) * 16 + nl];
                float v0 = xv.x, v1 = xv.y, v2 = xv.z, v3 = xv.w;
                float s01 = __shfl_xor((q & 1) ? v0 : v1, 16);
                float s23 = __shfl_xor((q & 1) ? v2 : v3, 16);
                float w0 = (q & 1) ? s01 : v0;
                float w1 = (q & 1) ? v1  : s01;
                float w2 = (q & 1) ? s23 : v2;
                float w3 = (q & 1) ? v3  : s23;
                float r02 = __shfl_xor((q & 2) ? w0 : w2, 32);
                float r13 = __shfl_xor((q & 2) ? w1 : w3, 32);
                float u0 = (q & 2) ? r02 : w0;
                float u1 = (q & 2) ? r13 : w1;
                float u2 = (q & 2) ? w2  : r02;
                float u3 = (q & 2) ? w3  : r13;
                unsigned a0 = (unsigned)f2bf(u0) | ((unsigned)f2bf(u1) << 16);
                unsigned a1 = (unsigned)f2bf(u2) | ((unsigned)f2bf(u3) << 16);
                uint2* dst = reinterpret_cast<uint2*>(
                    &Xt[t][(4 * nl + q) * 72 + cbase]);
                *dst = make_uint2(a0, a1);
            }
        }
    }
    __syncthreads();

    short8 b0 = *reinterpret_cast<const short8*>(&Wl[(16 * w + nl) * 72 + q * 8]);
    short8 b1 = *reinterpret_cast<const short8*>(&Wl[(16 * w + nl) * 72 + (4 + q) * 8]);
    const int h = 16 * w + nl;
    const float bv = Bs[h];

    #pragma unroll
    for (int t = 0; t < 4; ++t) {
        #pragma unroll
        for (int mt = 0; mt < 4; ++mt) {
            f32x4 acc = (f32x4){0.f, 0.f, 0.f, 0.f};
            short8 a0 = *reinterpret_cast<const short8*>(
                &Xt[t][(16 * mt + nl) * 72 + q * 8]);
            short8 a1 = *reinterpret_cast<const short8*>(
                &Xt[t][(16 * mt + nl) * 72 + (4 + q) * 8]);
            acc = __builtin_amdgcn_mfma_f32_16x16x32_bf16(a0, b0, acc, 0, 0, 0);
            acc = __builtin_amdgcn_mfma_f32_16x16x32_bf16(a1, b1, acc, 0, 0, 0);
            unsigned lo = (unsigned)f2bf(acc[0] + bv) | ((unsigned)f2bf(acc[1] + bv) << 16);
            unsigned hi = (unsigned)f2bf(acc[2] + bv) | ((unsigned)f2bf(acc[3] + bv) << 16);
            uint2* dst = reinterpret_cast<uint2*>(
                &outb[((size_t)(b * HH + h) * TT + (t0 + t)) * FF + 16 * mt + 4 * q]);
            *dst = make_uint2(lo, hi);
        }
    }
}

// ---------------------------------------------------------------------------
// K2 (MFMA): V[b,t,h,d] = (1/8) * sum_f Qb[t,f] * Kb[t+d-31,f]   (unchanged)
// ---------------------------------------------------------------------------
__global__ __launch_bounds__(256) void k_scores(
    const unsigned short* __restrict__ Qb, const unsigned short* __restrict__ Kb,
    float* __restrict__ V)
{
    __shared__ unsigned short Ql[64 * 72];
    __shared__ unsigned short Kl[96 * 72];

    const int tid = threadIdx.x;
    const int t0  = blockIdx.x * 64;
    const int h   = blockIdx.y, b = blockIdx.z;

    const size_t base = ((size_t)(b * HH + h) * TT) * FF;

    #pragma unroll
    for (int it = 0; it < 5; ++it) {
        int idx = it * 256 + tid;
        if (idx < 512) {
            int r = idx >> 3, g = idx & 7;
            uint4 v = *reinterpret_cast<const uint4*>(Qb + base + (size_t)(t0 + r) * FF + g * 8);
            *reinterpret_cast<uint4*>(&Ql[r * 72 + g * 8]) = v;
        } else {
            int idx2 = idx - 512;
            int r = idx2 >> 3, g = idx2 & 7;
            int j = t0 - 31 + r;
            uint4 v = make_uint4(0u, 0u, 0u, 0u);
            if (j >= 0 && j < TT)
                v = *reinterpret_cast<const uint4*>(Kb + base + (size_t)j * FF + g * 8);
            *reinterpret_cast<uint4*>(&Kl[r * 72 + g * 8]) = v;
        }
    }
    __syncthreads();

    const int l = tid & 63;
    const int w = tid >> 6;
    const int q = l >> 4;
    const int nl = l & 15;

    short8 a0 = *reinterpret_cast<const short8*>(&Ql[(16 * w + nl) * 72 + q * 8]);
    short8 a1 = *reinterpret_cast<const short8*>(&Ql[(16 * w + nl) * 72 + (4 + q) * 8]);

    f32x4 acc[3];
    #pragma unroll
    for (int n = 0; n < 3; ++n) acc[n] = (f32x4){0.f, 0.f, 0.f, 0.f};

    #pragma unroll
    for (int n = 0; n < 3; ++n) {
        short8 b0 = *reinterpret_cast<const short8*>(
            &Kl[(16 * w + 16 * n + nl) * 72 + q * 8]);
        short8 b1 = *reinterpret_cast<const short8*>(
            &Kl[(16 * w + 16 * n + nl) * 72 + (4 + q) * 8]);
        acc[n] = __builtin_amdgcn_mfma_f32_16x16x32_bf16(a0, b0, acc[n], 0, 0, 0);
        acc[n] = __builtin_amdgcn_mfma_f32_16x16x32_bf16(a1, b1, acc[n], 0, 0, 0);
    }

    #pragma unroll
    for (int n = 0; n < 3; ++n) {
        #pragma unroll
        for (int r = 0; r < 4; ++r) {
            const int tloc = 16 * w + 4 * q + r;
            const int d = 16 * n + nl - 4 * q - r;
            if (d >= 0 && d < DD) {
                const int t = t0 + tloc;
                V[((size_t)(b * TT + t) * HH + h) * DD + d] = acc[n][r] * 0.125f;
            }
        }
    }
}

// ---------------------------------------------------------------------------
// K3: conv (5,3) over (t,d) reducing H -> softmax over d.
// Shuffle-free: d+-1 neighbors come from zero pads (h-slots 32..35 + front
// guard) via scalar LDS reads; hg-reduce + softmax via shfl_xor.
// ---------------------------------------------------------------------------
__global__ __launch_bounds__(256) void k_conv_softmax(
    const float* __restrict__ V, const float* __restrict__ wconv,
    const float* __restrict__ bconv, float* __restrict__ A)
{
    __shared__ float Vs[8 * 2304 + 8];  // [4 guard][row][h][36]; slots 32..35 zero
    __shared__ float wcs[960];          // [h][i][j]

    const int tid = threadIdx.x;
    const int t0 = blockIdx.x * 4, b = blockIdx.y;

    #pragma unroll
    for (int idx = tid; idx < 960; idx += 256) wcs[idx] = wconv[idx];
    if (tid == 0) *reinterpret_cast<float4*>(&Vs[0]) = make_float4(0.f, 0.f, 0.f, 0.f);
    #pragma unroll
    for (int it = 0; it < 2; ++it) {                 // zero the h pads
        int idx = it * 256 + tid;                    // [0,512): r, h
        int r = idx >> 6, h = idx & 63;
        *reinterpret_cast<float4*>(&Vs[4 + r * 2304 + h * 36 + 32]) =
            make_float4(0.f, 0.f, 0.f, 0.f);
    }

    const float4* vg = reinterpret_cast<const float4*>(V);
    #pragma unroll
    for (int it = 0; it < 16; ++it) {
        int idx = it * 256 + tid;          // [0, 4096)
        int r = idx >> 9, g = idx & 511;   // row, granule
        int h = g >> 3, d4 = g & 7;
        int tt = t0 - 4 + r;
        float4 v = make_float4(0.f, 0.f, 0.f, 0.f);
        if (tt >= 0) v = vg[((size_t)(b * TT) + tt) * 512 + g];
        *reinterpret_cast<float4*>(&Vs[4 + r * 2304 + h * 36 + d4 * 4]) = v;
    }
    __syncthreads();

    const int dq = tid & 7;
    const int hg = (tid >> 3) & 7;
    const int tt = tid >> 6;              // wave id = local t

    float px = 0.f, py = 0.f, pz = 0.f, pw = 0.f;
    #pragma unroll
    for (int i = 0; i < 5; ++i) {
        const int r = tt + i;
        #pragma unroll
        for (int hh = 0; hh < 8; ++hh) {
            const int h = hg + 8 * hh;
            const int base = 4 + r * 2304 + h * 36 + dq * 4;
            float4 cur = *reinterpret_cast<const float4*>(&Vs[base]);
            float pv = Vs[base - 1];
            float nx = Vs[base + 4];
            const float w0 = wcs[h * 15 + i * 3 + 0];
            const float w1 = wcs[h * 15 + i * 3 + 1];
            const float w2 = wcs[h * 15 + i * 3 + 2];
            px += w0 * pv    + w1 * cur.x + w2 * cur.y;
            py += w0 * cur.x + w1 * cur.y + w2 * cur.z;
            pz += w0 * cur.y + w1 * cur.z + w2 * cur.w;
            pw += w0 * cur.z + w1 * cur.w + w2 * nx;
        }
    }
    #pragma unroll
    for (int off = 8; off <= 32; off <<= 1) {
        px += __shfl_xor(px, off);
        py += __shfl_xor(py, off);
        pz += __shfl_xor(pz, off);
        pw += __shfl_xor(pw, off);
    }
    const float bc = bconv[0];
    px += bc; py += bc; pz += bc; pw += bc;
    float m = fmaxf(fmaxf(px, py), fmaxf(pz, pw));
    #pragma unroll
    for (int off = 1; off <= 4; off <<= 1) m = fmaxf(m, __shfl_xor(m, off));
    float ex = __expf(px - m), ey = __expf(py - m);
    float ez = __expf(pz - m), ew = __expf(pw - m);
    float s = ex + ey + ez + ew;
    #pragma unroll
    for (int off = 1; off <= 4; off <<= 1) s += __shfl_xor(s, off);
    const float inv = 1.f / s;
    if (hg == 0) {
        const int t = t0 + tt;
        float4 av = make_float4(ex * inv, ey * inv, ez * inv, ew * inv);
        *reinterpret_cast<float4*>(&A[((size_t)(b * TT) + t) * DD + 4 * dq]) = av;
    }
}

// ---------------------------------------------------------------------------
// K4 (MFMA, bf16x2): aligned[b,c,t,f] = sum_d A[b,t,d] * x_ref[b,c,t+d-31,f]
// Banded GEMM out[t][f] = sum_j Ab[t][j] * X[j][f], j local 0..95
// (global row = t0-31+jl; band: 0 <= jl - tl < 32).
// A-operand = X^T (hi+lo bf16 split, quad-shuffle transpose, m = f);
// B-operand = band-packed A weights bf16 (n = t). Epilogue: f-contiguous
// float4 stores (lane holds 4 consecutive f).
// ---------------------------------------------------------------------------
__global__ __launch_bounds__(256) void k_align(
    const float* __restrict__ x_ref, const float* __restrict__ A, float* __restrict__ out)
{
    __shared__ unsigned short XtH[64 * 96];   // [f][jl] pitch 96
    __shared__ unsigned short XtL[64 * 96];
    __shared__ unsigned short Ab[64 * 96];    // [tl][jl] pitch 96
    __shared__ float As[64 * 32];             // staged A rows

    const int tid = threadIdx.x;
    const int t0  = blockIdx.x * 64;
    const int c   = blockIdx.y, b = blockIdx.z;

    const int l  = tid & 63;
    const int w  = tid >> 6;
    const int q  = l >> 4;
    const int nl = l & 15;

    // ---- stage A rows (fp32) ----
    {
        const float4* ag = reinterpret_cast<const float4*>(A);
        #pragma unroll
        for (int it = 0; it < 2; ++it) {
            int idx = it * 256 + tid;          // [0,512): row i, granule d4
            int i = idx >> 3, d4 = idx & 7;
            *reinterpret_cast<float4*>(&As[i * 32 + 4 * d4]) =
                ag[((size_t)(b * TT) + t0 + i) * 8 + d4];
        }
    }

    // ---- stage X^T hi/lo via quad-shuffle transpose ----
    {
        const float4* xg = reinterpret_cast<const float4*>(
            x_ref + ((size_t)(b * CC + c) * TT) * FF);
        #pragma unroll
        for (int it = 0; it < 6; ++it) {
            const int jbase = it * 16 + 4 * w;
            const int j  = jbase + q;
            const int jg = t0 - 31 + j;
            float4 xv = make_float4(0.f, 0.f, 0.f, 0.f);
            if (jg >= 0 && jg < TT) xv = xg[(size_t)jg * 16 + nl];
            float v0 = xv.x, v1 = xv.y, v2 = xv.z, v3 = xv.w;
            float s01 = __shfl_xor((q & 1) ? v0 : v1, 16);
            float s23 = __shfl_xor((q & 1) ? v2 : v3, 16);
            float w0 = (q & 1) ? s01 : v0;
            float w1 = (q & 1) ? v1  : s01;
            float w2 = (q & 1) ? s23 : v2;
            float w3 = (q & 1) ? v3  : s23;
            float r02 = __shfl_xor((q & 2) ? w0 : w2, 32);
            float r13 = __shfl_xor((q & 2) ? w1 : w3, 32);
            float u0 = (q & 2) ? r02 : w0;
            float u1 = (q & 2) ? r13 : w1;
            float u2 = (q & 2) ? w2  : r02;
            float u3 = (q & 2) ? w3  : r13;
            // lane holds X[jbase+0..3][f = 4nl+q]
            unsigned short h0 = f2bf(u0), h1 = f2bf(u1), h2 = f2bf(u2), h3 = f2bf(u3);
            unsigned short g0 = f2bf(u0 - bf2f(h0)), g1 = f2bf(u1 - bf2f(h1));
            unsigned short g2 = f2bf(u2 - bf2f(h2)), g3 = f2bf(u3 - bf2f(h3));
            const int row = (4 * nl + q) * 96 + jbase;
            *reinterpret_cast<uint2*>(&XtH[row]) =
                make_uint2((unsigned)h0 | ((unsigned)h1 << 16),
                           (unsigned)h2 | ((unsigned)h3 << 16));
            *reinterpret_cast<uint2*>(&XtL[row]) =
                make_uint2((unsigned)g0 | ((unsigned)g1 << 16),
                           (unsigned)g2 | ((unsigned)g3 << 16));
        }
    }
    __syncthreads();

    // ---- pack band weights: Ab[tl][jl] = A[tl][jl-tl] in-band else 0 ----
    {
        unsigned* ab32 = reinterpret_cast<unsigned*>(Ab);
        #pragma unroll
        for (int it = 0; it < 12; ++it) {
            int idx = it * 256 + tid;          // [0, 3072): tl, jl2
            int tl = idx / 48, jl2 = idx - tl * 48;
            int d0 = 2 * jl2 - tl;
            int d1 = d0 + 1;
            float w0 = (d0 >= 0 && d0 < 32) ? As[tl * 32 + d0] : 0.f;
            float w1 = (d1 >= 0 && d1 < 32) ? As[tl * 32 + d1] : 0.f;
            ab32[tl * 48 + jl2] = (unsigned)f2bf(w0) | ((unsigned)f2bf(w1) << 16);
        }
    }
    __syncthreads();

    // ---- MFMA: wave w = f-tile; acc[n] = out[f-tile][t-tile n] ----
    f32x4 acc[4];
    #pragma unroll
    for (int n = 0; n < 4; ++n) acc[n] = (f32x4){0.f, 0.f, 0.f, 0.f};

    #pragma unroll
    for (int kt = 0; kt < 3; ++kt) {
        const int k0 = 32 * kt + 8 * q;
        short8 aH = *reinterpret_cast<const short8*>(&XtH[(16 * w + nl) * 96 + k0]);
        short8 aL = *reinterpret_cast<const short8*>(&XtL[(16 * w + nl) * 96 + k0]);
        #pragma unroll
        for (int n = 0; n < 4; ++n) {
            short8 bA = *reinterpret_cast<const short8*>(&Ab[(16 * n + nl) * 96 + k0]);
            acc[n] = __builtin_amdgcn_mfma_f32_16x16x32_bf16(aH, bA, acc[n], 0, 0, 0);
            acc[n] = __builtin_amdgcn_mfma_f32_16x16x32_bf16(aL, bA, acc[n], 0, 0, 0);
        }
    }

    // ---- store: f = 16w + 4q + r, t = t0 + 16n + nl ----
    float4* o4 = reinterpret_cast<float4*>(out);
    #pragma unroll
    for (int n = 0; n < 4; ++n) {
        const size_t row = (size_t)(b * CC + c) * TT + t0 + 16 * n + nl;
        o4[row * 16 + 4 * w + q] = make_float4(acc[n][0], acc[n][1], acc[n][2], acc[n][3]);
    }
}

// ---------------------------------------------------------------------------
extern "C" void kernel_launch(void* const* d_in, const int* in_sizes, int n_in,
                              void* d_out, int out_size, void* d_ws, size_t ws_size,
                              hipStream_t stream)
{
    const float* x_mic  = (const float*)d_in[0];
    const float* x_ref  = (const float*)d_in[1];
    const float* w_mic  = (const float*)d_in[2];
    const float* b_mic  = (const float*)d_in[3];
    const float* w_ref  = (const float*)d_in[4];
    const float* b_ref  = (const float*)d_in[5];
    const float* w_conv = (const float*)d_in[6];
    const float* b_conv = (const float*)d_in[7];
    float* out = (float*)d_out;

    unsigned short* Qb = (unsigned short*)d_ws;          // B*H*T*F bf16
    unsigned short* Kb = Qb + 4194304;                   // B*H*T*F bf16
    float* V = (float*)(Kb + 4194304);                   // B*T*H*D fp32
    float* A = V + 2097152;                              // B*T*D fp32

    k_qk<<<dim3(BB * (TT / 4), 2), 256, 0, stream>>>(
        x_mic, x_ref, w_mic, b_mic, w_ref, b_ref, Qb, Kb);
    k_scores<<<dim3(TT / 64, HH, BB), 256, 0, stream>>>(Qb, Kb, V);
    k_conv_softmax<<<dim3(TT / 4, BB), 256, 0, stream>>>(V, w_conv, b_conv, A);
    k_align<<<dim3(TT / 64, CC, BB), 256, 0, stream>>>(x_ref, A, out);
}

// Round 8
// 126.525 us; speedup vs baseline: 1.0301x; 1.0301x over previous
//
#include <hip/hip_runtime.h>
#include <hip/hip_bf16.h>

#define BB 2
#define CC 64
#define HH 64
#define TT 512
#define FF 64
#define DD 32

typedef short short8 __attribute__((ext_vector_type(8)));
typedef float f32x4  __attribute__((ext_vector_type(4)));

__device__ __forceinline__ unsigned short f2bf(float x) {
    union { float f; unsigned u; } v; v.f = x;
    unsigned r = v.u + 0x7FFFu + ((v.u >> 16) & 1u);   // RNE
    return (unsigned short)(r >> 16);
}

// ---------------------------------------------------------------------------
// K1 (MFMA): Qb = bf16(w_mic @ x_mic + b_mic); Kb likewise.
// Operand order: A = xT (m=f), B = W (n=h)  ->  lane holds 4 CONSECUTIVE f
// (row = 4q+reg) for one h (col = lane&15): epilogue is 8 uint2 stores.
// ---------------------------------------------------------------------------
__global__ __launch_bounds__(256) void k_qk(
    const float* __restrict__ x_mic, const float* __restrict__ x_ref,
    const float* __restrict__ w_mic, const float* __restrict__ b_mic,
    const float* __restrict__ w_ref, const float* __restrict__ b_ref,
    unsigned short* __restrict__ Qb, unsigned short* __restrict__ Kb)
{
    __shared__ unsigned short Wl[64 * 72];       // [h][c] pitch 72
    __shared__ unsigned short Xt[2][64 * 72];    // [t][f][c] pitch 72
    __shared__ float Bs[64];

    const int tid = threadIdx.x;
    const int b   = blockIdx.x >> 8;
    const int t0  = (blockIdx.x & 255) * 2;
    const int which = blockIdx.y;

    const float* xsrc = which ? x_ref : x_mic;
    const float* wsrc = which ? w_ref : w_mic;
    const float* bsrc = which ? b_ref : b_mic;
    unsigned short* outb = which ? Kb : Qb;

    const int l  = tid & 63;
    const int w  = tid >> 6;
    const int q  = l >> 4;        // quad index 0..3
    const int nl = l & 15;

    // ---- stage W as bf16 [h][c] pitch 72 ----
    {
        const float4* wg = reinterpret_cast<const float4*>(wsrc);
        const int h  = tid >> 2;
        #pragma unroll
        for (int p = 0; p < 4; ++p) {
            const int c0 = (tid & 3) * 4 + p * 16;
            float4 wv = wg[h * 16 + (c0 >> 2)];
            unsigned w0 = (unsigned)f2bf(wv.x) | ((unsigned)f2bf(wv.y) << 16);
            unsigned w1 = (unsigned)f2bf(wv.z) | ((unsigned)f2bf(wv.w) << 16);
            uint2* dst = reinterpret_cast<uint2*>(&Wl[h * 72 + c0]);
            *dst = make_uint2(w0, w1);
        }
    }
    if (tid < 64) Bs[tid] = bsrc[tid];

    // ---- stage x transposed: xT[f][c] bf16, quad-shuffle 4x4 transpose ----
    {
        const float4* xg = reinterpret_cast<const float4*>(
            xsrc + (size_t)b * CC * TT * FF);
        #pragma unroll
        for (int t = 0; t < 2; ++t) {
            #pragma unroll
            for (int p = 0; p < 4; ++p) {
                const int cbase = p * 16 + 4 * w;
                const int c     = cbase + q;
                float4 xv = xg[((size_t)c * TT + (t0 + t)) * 16 + nl];
                float v0 = xv.x, v1 = xv.y, v2 = xv.z, v3 = xv.w;
                float s01 = __shfl_xor((q & 1) ? v0 : v1, 16);
                float s23 = __shfl_xor((q & 1) ? v2 : v3, 16);
                float w0 = (q & 1) ? s01 : v0;
                float w1 = (q & 1) ? v1  : s01;
                float w2 = (q & 1) ? s23 : v2;
                float w3 = (q & 1) ? v3  : s23;
                float r02 = __shfl_xor((q & 2) ? w0 : w2, 32);
                float r13 = __shfl_xor((q & 2) ? w1 : w3, 32);
                float u0 = (q & 2) ? r02 : w0;
                float u1 = (q & 2) ? r13 : w1;
                float u2 = (q & 2) ? w2  : r02;
                float u3 = (q & 2) ? w3  : r13;
                unsigned a0 = (unsigned)f2bf(u0) | ((unsigned)f2bf(u1) << 16);
                unsigned a1 = (unsigned)f2bf(u2) | ((unsigned)f2bf(u3) << 16);
                uint2* dst = reinterpret_cast<uint2*>(
                    &Xt[t][(4 * nl + q) * 72 + cbase]);
                *dst = make_uint2(a0, a1);
            }
        }
    }
    __syncthreads();

    // B-frags: W rows h = 16w + nl (cached for both t)
    short8 b0 = *reinterpret_cast<const short8*>(&Wl[(16 * w + nl) * 72 + q * 8]);
    short8 b1 = *reinterpret_cast<const short8*>(&Wl[(16 * w + nl) * 72 + (4 + q) * 8]);
    const int h = 16 * w + nl;
    const float bv = Bs[h];

    #pragma unroll
    for (int t = 0; t < 2; ++t) {
        #pragma unroll
        for (int mt = 0; mt < 4; ++mt) {
            f32x4 acc = (f32x4){0.f, 0.f, 0.f, 0.f};
            short8 a0 = *reinterpret_cast<const short8*>(
                &Xt[t][(16 * mt + nl) * 72 + q * 8]);
            short8 a1 = *reinterpret_cast<const short8*>(
                &Xt[t][(16 * mt + nl) * 72 + (4 + q) * 8]);
            acc = __builtin_amdgcn_mfma_f32_16x16x32_bf16(a0, b0, acc, 0, 0, 0);
            acc = __builtin_amdgcn_mfma_f32_16x16x32_bf16(a1, b1, acc, 0, 0, 0);
            // lane: f = 16mt + 4q + r, h = 16w + nl
            unsigned lo = (unsigned)f2bf(acc[0] + bv) | ((unsigned)f2bf(acc[1] + bv) << 16);
            unsigned hi = (unsigned)f2bf(acc[2] + bv) | ((unsigned)f2bf(acc[3] + bv) << 16);
            uint2* dst = reinterpret_cast<uint2*>(
                &outb[((size_t)(b * HH + h) * TT + (t0 + t)) * FF + 16 * mt + 4 * q]);
            *dst = make_uint2(lo, hi);
        }
    }
}

// ---------------------------------------------------------------------------
// K2 (MFMA): V[b,t,h,d] = (1/8) * sum_f Qb[t,f] * Kb[t+d-31,f]
// ---------------------------------------------------------------------------
__global__ __launch_bounds__(256) void k_scores(
    const unsigned short* __restrict__ Qb, const unsigned short* __restrict__ Kb,
    float* __restrict__ V)
{
    __shared__ unsigned short Ql[64 * 72];
    __shared__ unsigned short Kl[96 * 72];

    const int tid = threadIdx.x;
    const int t0  = blockIdx.x * 64;
    const int h   = blockIdx.y, b = blockIdx.z;

    const size_t base = ((size_t)(b * HH + h) * TT) * FF;

    #pragma unroll
    for (int it = 0; it < 5; ++it) {
        int idx = it * 256 + tid;
        if (idx < 512) {
            int r = idx >> 3, g = idx & 7;
            uint4 v = *reinterpret_cast<const uint4*>(Qb + base + (size_t)(t0 + r) * FF + g * 8);
            *reinterpret_cast<uint4*>(&Ql[r * 72 + g * 8]) = v;
        } else {
            int idx2 = idx - 512;
            int r = idx2 >> 3, g = idx2 & 7;
            int j = t0 - 31 + r;
            uint4 v = make_uint4(0u, 0u, 0u, 0u);
            if (j >= 0 && j < TT)
                v = *reinterpret_cast<const uint4*>(Kb + base + (size_t)j * FF + g * 8);
            *reinterpret_cast<uint4*>(&Kl[r * 72 + g * 8]) = v;
        }
    }
    __syncthreads();

    const int l = tid & 63;
    const int w = tid >> 6;
    const int q = l >> 4;
    const int nl = l & 15;

    short8 a0 = *reinterpret_cast<const short8*>(&Ql[(16 * w + nl) * 72 + q * 8]);
    short8 a1 = *reinterpret_cast<const short8*>(&Ql[(16 * w + nl) * 72 + (4 + q) * 8]);

    f32x4 acc[3];
    #pragma unroll
    for (int n = 0; n < 3; ++n) acc[n] = (f32x4){0.f, 0.f, 0.f, 0.f};

    #pragma unroll
    for (int n = 0; n < 3; ++n) {
        short8 b0 = *reinterpret_cast<const short8*>(
            &Kl[(16 * w + 16 * n + nl) * 72 + q * 8]);
        short8 b1 = *reinterpret_cast<const short8*>(
            &Kl[(16 * w + 16 * n + nl) * 72 + (4 + q) * 8]);
        acc[n] = __builtin_amdgcn_mfma_f32_16x16x32_bf16(a0, b0, acc[n], 0, 0, 0);
        acc[n] = __builtin_amdgcn_mfma_f32_16x16x32_bf16(a1, b1, acc[n], 0, 0, 0);
    }

    #pragma unroll
    for (int n = 0; n < 3; ++n) {
        #pragma unroll
        for (int r = 0; r < 4; ++r) {
            const int tloc = 16 * w + 4 * q + r;
            const int d = 16 * n + nl - 4 * q - r;
            if (d >= 0 && d < DD) {
                const int t = t0 + tloc;
                V[((size_t)(b * TT + t) * HH + h) * DD + d] = acc[n][r] * 0.125f;
            }
        }
    }
}

// ---------------------------------------------------------------------------
// K3: conv (5,3) over (t,d) reducing H -> softmax over d.
// Block = 4 t, 256 thr. Thread = (dq = tid&7: d-quad, hg = (tid>>3)&7:
// h-partial, wave = one t). 1 b128 per (i,h); d+-1 via shfl; hg-reduce +
// softmax fully via shfl_xor. V rows staged [row][h][36].
// ---------------------------------------------------------------------------
__global__ __launch_bounds__(256) void k_conv_softmax(
    const float* __restrict__ V, const float* __restrict__ wconv,
    const float* __restrict__ bconv, float* __restrict__ A)
{
    __shared__ float Vs[8 * 2304];      // [row][h][36]
    __shared__ float wcs[960];          // [h][i][j]

    const int tid = threadIdx.x;
    const int t0 = blockIdx.x * 4, b = blockIdx.y;

    #pragma unroll
    for (int idx = tid; idx < 960; idx += 256) wcs[idx] = wconv[idx];

    const float4* vg = reinterpret_cast<const float4*>(V);
    #pragma unroll
    for (int it = 0; it < 16; ++it) {
        int idx = it * 256 + tid;          // [0, 4096)
        int r = idx >> 9, g = idx & 511;   // row, f4-granule
        int h = g >> 3, d4 = g & 7;
        int tt = t0 - 4 + r;
        float4 v = make_float4(0.f, 0.f, 0.f, 0.f);
        if (tt >= 0) v = vg[((size_t)(b * TT) + tt) * 512 + g];
        *reinterpret_cast<float4*>(&Vs[r * 2304 + h * 36 + d4 * 4]) = v;
    }
    __syncthreads();

    const int dq = tid & 7;
    const int hg = (tid >> 3) & 7;
    const int tt = tid >> 6;              // wave id = local t

    float px = 0.f, py = 0.f, pz = 0.f, pw = 0.f;
    #pragma unroll
    for (int i = 0; i < 5; ++i) {
        const int r = tt + i;             // staged row
        #pragma unroll
        for (int hh = 0; hh < 8; ++hh) {
            const int h = hg + 8 * hh;
            float4 cur = *reinterpret_cast<const float4*>(
                &Vs[r * 2304 + h * 36 + dq * 4]);
            float pv = __shfl_up(cur.w, 1);
            float nx = __shfl_down(cur.x, 1);
            if (dq == 0) pv = 0.f;
            if (dq == 7) nx = 0.f;
            const float w0 = wcs[h * 15 + i * 3 + 0];
            const float w1 = wcs[h * 15 + i * 3 + 1];
            const float w2 = wcs[h * 15 + i * 3 + 2];
            px += w0 * pv    + w1 * cur.x + w2 * cur.y;
            py += w0 * cur.x + w1 * cur.y + w2 * cur.z;
            pz += w0 * cur.y + w1 * cur.z + w2 * cur.w;
            pw += w0 * cur.z + w1 * cur.w + w2 * nx;
        }
    }
    // reduce over hg (lane bits 3,4,5)
    #pragma unroll
    for (int off = 8; off <= 32; off <<= 1) {
        px += __shfl_xor(px, off);
        py += __shfl_xor(py, off);
        pz += __shfl_xor(pz, off);
        pw += __shfl_xor(pw, off);
    }
    const float bc = bconv[0];
    px += bc; py += bc; pz += bc; pw += bc;
    // softmax over the 32 d (4 per lane x 8 dq); replicated over hg
    float m = fmaxf(fmaxf(px, py), fmaxf(pz, pw));
    #pragma unroll
    for (int off = 1; off <= 4; off <<= 1) m = fmaxf(m, __shfl_xor(m, off));
    float ex = __expf(px - m), ey = __expf(py - m);
    float ez = __expf(pz - m), ew = __expf(pw - m);
    float s = ex + ey + ez + ew;
    #pragma unroll
    for (int off = 1; off <= 4; off <<= 1) s += __shfl_xor(s, off);
    const float inv = 1.f / s;
    if (hg == 0) {
        const int t = t0 + tt;
        float4 av = make_float4(ex * inv, ey * inv, ez * inv, ew * inv);
        *reinterpret_cast<float4*>(&A[((size_t)(b * TT) + t) * DD + 4 * dq]) = av;
    }
}

// ---------------------------------------------------------------------------
// K4: aligned[b,c,t,f] = sum_d A[b,t,d] * x_ref[b,c,t+d-31,f]
// Block = (t-tile 64, c, b), 256 thr: f4 = tid&15, bi = tid>>4 (4 out rows).
// Band weights pre-packed: Ap[bi][rr] = float4 of A[4bi+r][rr-r] (zeros
// outside) -> inner loop = 1 X-b128 + 1 Ap-b128-broadcast per rr for 16 FMA.
// ---------------------------------------------------------------------------
__global__ __launch_bounds__(256) void k_align(
    const float* __restrict__ x_ref, const float* __restrict__ A, float* __restrict__ out)
{
    __shared__ float Xs[95 * 68];       // [row][f] pad 68
    __shared__ float As[64 * 36];       // [i][d] staging
    __shared__ float Ap[16 * 37 * 4];   // packed float4 [bi][rr], pitch 37

    const int tid = threadIdx.x;
    const int t0  = blockIdx.x * 64;
    const int c   = blockIdx.y, b = blockIdx.z;

    const float4* xg = reinterpret_cast<const float4*>(
        x_ref + ((size_t)(b * CC + c) * TT) * FF);
    float4* xs4 = reinterpret_cast<float4*>(Xs);
    #pragma unroll
    for (int it = 0; it < 6; ++it) {
        int idx = it * 256 + tid;
        if (idx < 95 * 16) {
            int r = idx >> 4, f4 = idx & 15;
            int tt = t0 - 31 + r;
            float4 v = make_float4(0.f, 0.f, 0.f, 0.f);
            if (tt >= 0) v = xg[tt * 16 + f4];
            xs4[r * 17 + f4] = v;
        }
    }
    #pragma unroll
    for (int it = 0; it < 2; ++it) {
        int idx = it * 256 + tid;          // 512 granules = 64 rows x 8
        int i = idx >> 3, d4 = idx & 7;
        *reinterpret_cast<float4*>(&As[i * 36 + 4 * d4]) =
            *reinterpret_cast<const float4*>(&A[((size_t)(b * TT) + t0 + i) * DD + 4 * d4]);
    }
    __syncthreads();
    #pragma unroll
    for (int it = 0; it < 3; ++it) {
        int idx = it * 256 + tid;
        if (idx < 16 * 37) {
            int bi = idx / 37, rr = idx - bi * 37;
            float wv[4];
            #pragma unroll
            for (int r = 0; r < 4; ++r) {
                int d = rr - r;
                wv[r] = (d >= 0 && d < 32) ? As[(4 * bi + r) * 36 + d] : 0.f;
            }
            float4* dst = reinterpret_cast<float4*>(&Ap[(bi * 37 + rr) * 4]);
            *dst = make_float4(wv[0], wv[1], wv[2], wv[3]);
        }
    }
    __syncthreads();

    const int f4 = tid & 15;
    const int bi = tid >> 4;

    float4 acc0 = make_float4(0.f, 0.f, 0.f, 0.f);
    float4 acc1 = make_float4(0.f, 0.f, 0.f, 0.f);
    float4 acc2 = make_float4(0.f, 0.f, 0.f, 0.f);
    float4 acc3 = make_float4(0.f, 0.f, 0.f, 0.f);

    #pragma unroll 7
    for (int rr = 0; rr < 35; ++rr) {
        float4 W4 = *reinterpret_cast<const float4*>(&Ap[(bi * 37 + rr) * 4]);
        float4 X4 = xs4[(4 * bi + rr) * 17 + f4];
        acc0.x += W4.x * X4.x; acc0.y += W4.x * X4.y; acc0.z += W4.x * X4.z; acc0.w += W4.x * X4.w;
        acc1.x += W4.y * X4.x; acc1.y += W4.y * X4.y; acc1.z += W4.y * X4.z; acc1.w += W4.y * X4.w;
        acc2.x += W4.z * X4.x; acc2.y += W4.z * X4.y; acc2.z += W4.z * X4.z; acc2.w += W4.z * X4.w;
        acc3.x += W4.w * X4.x; acc3.y += W4.w * X4.y; acc3.z += W4.w * X4.z; acc3.w += W4.w * X4.w;
    }

    float4* o4 = reinterpret_cast<float4*>(out);
    const size_t obase = ((size_t)(b * CC + c) * TT + t0 + 4 * bi) * 16 + f4;
    o4[obase +  0] = acc0;
    o4[obase + 16] = acc1;
    o4[obase + 32] = acc2;
    o4[obase + 48] = acc3;
}

// ---------------------------------------------------------------------------
extern "C" void kernel_launch(void* const* d_in, const int* in_sizes, int n_in,
                              void* d_out, int out_size, void* d_ws, size_t ws_size,
                              hipStream_t stream)
{
    const float* x_mic  = (const float*)d_in[0];
    const float* x_ref  = (const float*)d_in[1];
    const float* w_mic  = (const float*)d_in[2];
    const float* b_mic  = (const float*)d_in[3];
    const float* w_ref  = (const float*)d_in[4];
    const float* b_ref  = (const float*)d_in[5];
    const float* w_conv = (const float*)d_in[6];
    const float* b_conv = (const float*)d_in[7];
    float* out = (float*)d_out;

    unsigned short* Qb = (unsigned short*)d_ws;          // B*H*T*F bf16
    unsigned short* Kb = Qb + 4194304;                   // B*H*T*F bf16
    float* V = (float*)(Kb + 4194304);                   // B*T*H*D fp32
    float* A = V + 2097152;                              // B*T*D fp32

    k_qk<<<dim3(BB * (TT / 2), 2), 256, 0, stream>>>(
        x_mic, x_ref, w_mic, b_mic, w_ref, b_ref, Qb, Kb);
    k_scores<<<dim3(TT / 64, HH, BB), 256, 0, stream>>>(Qb, Kb, V);
    k_conv_softmax<<<dim3(TT / 4, BB), 256, 0, stream>>>(V, w_conv, b_conv, A);
    k_align<<<dim3(TT / 64, CC, BB), 256, 0, stream>>>(x_ref, A, out);
}